// Round 11
// baseline (97.224 us; speedup 1.0000x reference)
//
#include <hip/hip_runtime.h>

// MVB (minimum-variance beamformer), fp32. Round 11: channel-split x
// cache-gather (the untested combination).
//
// Evidence: R6 (channel-split x LDS) no gain -> LDS machinery bound.
// R10 (cache-gather x 1 wave/SIMD) best -> gathers latency-exposed, only
// 1 wave/SIMD (pixel count caps TLP at 1 px/thread). TA floor ~8.5 us vs
// ~24 us measured => latency, not throughput. This round: 2 waves/SIMD by
// splitting channels across waves, gathering straight from L1/L2 (no
// staging), merging partial lag-sums via the R6/R9-verified algebra through
// a 25 KB LDS exchange (one barrier only).
//  - 512 blocks x 256 threads: half = tid>>7 (ch 0-63 / 64-127),
//    px = tid&127; each thread: 4 chunks of 16 channels.
//  - chunk: 16 coalesced drx loads -> 16 independent 8-B gathers
//    (global_load_dwordx2; 32 loads in flight) -> static window FMAs.
//  - combine: F[d] += F_lo[d] + sum_{i<d} head_hi[i]*win_lo[16-d+i];
//    hi threads solve (rsqrt-Cholesky + 2 triangular solves) and store.

namespace {

constexpr int kB  = 2;
constexpr int kC  = 128;
constexpr int kNS = 1024;
constexpr int kNZ = 256;
constexpr int kNX = 128;
constexpr int kZX = kNZ * kNX;        // 32768
constexpr int kTPB = 256;

// packed upper-triangular index, l <= k, 16x16 -> 136 entries
__device__ __host__ constexpr int tri(int l, int k) {
  return l * 16 - (l * (l - 1)) / 2 + (k - l);
}

template <bool HEAD>
__device__ __forceinline__ void chunk16(
    const float* __restrict__ rfq,       // rf base of this 16-row chunk
    const float* __restrict__ drxp, int cbase, float kk, float base,
    float (&F)[16], float (&win)[16], float (&head)[16], float& Sall) {
  // 16 coalesced per-channel delays (independent, deep in flight)
  float dr[16];
#pragma unroll
  for (int r = 0; r < 16; ++r) dr[r] = drxp[(size_t)(cbase + r) * kZX];

  // 16 independent 8-byte gathers from the L1/L2-resident rf rows
  float2 vv[16];
  float fr[16];
#pragma unroll
  for (int r = 0; r < 16; ++r) {
    float pos = fmaf(kk, dr[r], base);
    pos = fminf(fmaxf(pos, 0.0f), 1023.0f);
    int i0 = (int)pos;                   // pos >= 0: trunc == floor
    i0 = min(i0, kNS - 2);               // pos==1023 -> frac==1.0
    fr[r] = pos - (float)i0;
    __builtin_memcpy(&vv[r], rfq + r * kNS + i0, 8);   // v0,v1 adjacent
  }

  // window-FMA bursts; chunk aligns with L_SUB so indices are static
#pragma unroll
  for (int r = 0; r < 16; ++r) {
    float v = fmaf(fr[r], vv[r].y - vv[r].x, vv[r].x);
    Sall += v;
    F[0] = fmaf(v, v, F[0]);
    if constexpr (HEAD) {
#pragma unroll
      for (int d = 1; d <= r; ++d) F[d] = fmaf(v, win[r - d], F[d]);
      head[r] = v;
    } else {
#pragma unroll
      for (int d = 1; d < 16; ++d) F[d] = fmaf(v, win[(r - d) & 15], F[d]);
    }
    win[r] = v;
  }
}

// ------------- Fused kernel: split cache-gather + combine + solve ----------
__global__ __launch_bounds__(kTPB, 1) void mvb_kernel(
    const float* __restrict__ rf, const float* __restrict__ t0,
    const float* __restrict__ d_tx, const float* __restrict__ d_rx,
    const float* __restrict__ fs_p, const float* __restrict__ c0_p,
    float* __restrict__ out) {
  __shared__ float xch[49 * 128];      // 25 KB lo->hi exchange

  const int tid = threadIdx.x;
  const int half = tid >> 7;           // 0: ch 0-63, 1: ch 64-127
  const int px = tid & 127;
  const int z = blockIdx.x & (kNZ - 1);
  const int b = blockIdx.x >> 8;       // kNZ == 256
  const int pix = (int)((size_t)b * kZX + z * kNX + px);

  const float fs = fs_p[0];
  const float c0 = c0_p[0];
  const float kk = fs / c0;
  const float base = fs * (d_tx[pix] / c0 + t0[b]);

  const float* rfh = rf + (size_t)b * kC * kNS + (size_t)half * 64 * kNS;
  const float* drxp =
      d_rx + (size_t)half * 64 * kZX + (size_t)z * kNX + px;

  float F[16], win[16], head[16];
  float Sall = 0.0f;
#pragma unroll
  for (int i = 0; i < 16; ++i) F[i] = 0.0f;

  // ---- phase A: 4 chunks of 16 channels (this thread's half) ----
  chunk16<true>(rfh, drxp, 0, kk, base, F, win, head, Sall);
#pragma unroll 1
  for (int q = 1; q < 4; ++q)
    chunk16<false>(rfh + (size_t)q * 16 * kNS, drxp, q * 16, kk, base, F,
                   win, head, Sall);
  // per half: head[i] = x_{h*64+i}, win[i] = x_{h*64+48+i},
  //           F[d] = sum_{j in half, j-d in half} x_j x_{j-d}

  // ---- exchange: lo threads export their 49-float summary ----
  if (half == 0) {
#pragma unroll
    for (int i = 0; i < 16; ++i) xch[i * 128 + px] = F[i];
#pragma unroll
    for (int i = 0; i < 16; ++i) xch[(16 + i) * 128 + px] = win[i];
#pragma unroll
    for (int i = 0; i < 16; ++i) xch[(32 + i) * 128 + px] = head[i];
    xch[48 * 128 + px] = Sall;
  }
  __syncthreads();                     // the only barrier
  if (half == 0) return;               // hi threads combine + solve

  float hlo[16];                       // global head = lo's head
  {
    float wlo[16];
#pragma unroll
    for (int i = 0; i < 16; ++i) wlo[i] = xch[(16 + i) * 128 + px];
#pragma unroll
    for (int i = 0; i < 16; ++i) hlo[i] = xch[(32 + i) * 128 + px];
    Sall += xch[48 * 128 + px];
    F[0] += xch[0 * 128 + px];
#pragma unroll
    for (int d = 1; d < 16; ++d) {
      float s = xch[d * 128 + px];     // F_lo[d]
#pragma unroll
      for (int i = 0; i < d; ++i) s = fmaf(head[i], wlo[16 - d + i], s);
      F[d] += s;                       // + cross terms head_hi x win_lo
    }
  }
  // now: hlo = x_{0..15}, win = x_{112..127}, F[d] = full lag sums

  // ---- assemble R (unscaled; packed upper triangle) ----
  float Ru[136];
#pragma unroll
  for (int d = 0; d < 16; ++d) {
    float t0s = 0.0f;                  // tail beyond window of l=0
#pragma unroll
    for (int i = d + 1; i < 16; ++i) t0s = fmaf(win[i - d], win[i], t0s);
    Ru[tri(0, d)] = F[d] - t0s;
#pragma unroll
    for (int l = 1; l < 16 - d; ++l)
      Ru[tri(l, l + d)] = Ru[tri(l - 1, l - 1 + d)] -
                          hlo[l - 1] * hlo[l - 1 + d] +
                          win[l] * win[l + d];
  }

  // diagonal loading: += DL * trace/16
  float tr = 0.0f;
#pragma unroll
  for (int l = 0; l < 16; ++l) tr += Ru[tri(l, l)];
  const float dl = tr * (0.05f / 16.0f);
#pragma unroll
  for (int l = 0; l < 16; ++l) Ru[tri(l, l)] += dl;

  // x (unscaled window sums): X[l] = sum_{j=l}^{l+112} xf[j]
  float X[16];
  {
    float s = Sall;
#pragma unroll
    for (int i = 1; i < 16; ++i) s -= win[i];
    X[0] = s;
#pragma unroll
    for (int l = 1; l < 16; ++l) X[l] = X[l - 1] - hlo[l - 1] + win[l];
  }

  // ---- Cholesky R = L L^T (rsqrt form), L[i][j] at Ru[tri(j,i)] ----
  float inv[16];
#pragma unroll
  for (int j = 0; j < 16; ++j) {
    float d = Ru[tri(j, j)];
#pragma unroll
    for (int p = 0; p < j; ++p) d = fmaf(-Ru[tri(p, j)], Ru[tri(p, j)], d);
    inv[j] = rsqrtf(d);
#pragma unroll
    for (int i = j + 1; i < 16; ++i) {
      float s = Ru[tri(j, i)];
#pragma unroll
      for (int p = 0; p < j; ++p) s = fmaf(-Ru[tri(p, i)], Ru[tri(p, j)], s);
      Ru[tri(j, i)] = s * inv[j];
    }
  }

  // forward solve L y = 1
  float yv[16];
#pragma unroll
  for (int i = 0; i < 16; ++i) {
    float s = 1.0f;
#pragma unroll
    for (int j = 0; j < i; ++j) s = fmaf(-Ru[tri(j, i)], yv[j], s);
    yv[i] = s * inv[i];
  }
  // back solve L^T u = y
  float u[16];
#pragma unroll
  for (int i = 15; i >= 0; --i) {
    float s = yv[i];
#pragma unroll
    for (int j = i + 1; j < 16; ++j) s = fmaf(-Ru[tri(i, j)], u[j], s);
    u[i] = s * inv[i];
  }

  float su = 0.0f, dot = 0.0f;
#pragma unroll
  for (int i = 0; i < 16; ++i) {
    su += u[i];
    dot = fmaf(u[i], X[i], dot);
  }
  // y = dot/(M*su + 1e-10)  (matches reference up to scale algebra)
  out[pix] = dot / (113.0f * su + 1e-10f);
}

}  // namespace

extern "C" void kernel_launch(void* const* d_in, const int* in_sizes, int n_in,
                              void* d_out, int out_size, void* d_ws,
                              size_t ws_size, hipStream_t stream) {
  const float* rf   = (const float*)d_in[0];
  const float* t0   = (const float*)d_in[1];
  const float* d_tx = (const float*)d_in[2];
  const float* d_rx = (const float*)d_in[3];
  const float* fs   = (const float*)d_in[4];
  // d_in[5] = f0 (unused), d_in[7] = apod (unused by reference)
  const float* c0   = (const float*)d_in[6];
  float* out = (float*)d_out;

  hipLaunchKernelGGL(mvb_kernel, dim3(kB * kNZ), dim3(kTPB), 0, stream,
                     rf, t0, d_tx, d_rx, fs, c0, out);
}